// Round 1
// baseline (1354.773 us; speedup 1.0000x reference)
//
#include <hip/hip_runtime.h>
#include <cstddef>

#define NN 12288
#define FF 512

using half8 = __attribute__((ext_vector_type(8))) _Float16;
using f32x4 = __attribute__((ext_vector_type(4))) float;

constexpr int BM = 64;              // query rows per block
constexpr int BN = 64;              // keys per tile
constexpr int KV_STRIDE = 520;      // fp16 elems per kv row (512 + 8 pad)
constexpr float MASK_NEG = -1e9f;   // matches Keras additive mask constant

// ---------------- prepass: features fp32 -> fp16 into workspace ----------------
__global__ void cvt_feat_kernel(const float* __restrict__ in, _Float16* __restrict__ out) {
    const size_t i = ((size_t)blockIdx.x * blockDim.x + threadIdx.x) * 8;
    float4 x = *reinterpret_cast<const float4*>(in + i);
    float4 y = *reinterpret_cast<const float4*>(in + i + 4);
    half8 h;
    h[0] = (_Float16)x.x; h[1] = (_Float16)x.y; h[2] = (_Float16)x.z; h[3] = (_Float16)x.w;
    h[4] = (_Float16)y.x; h[5] = (_Float16)y.y; h[6] = (_Float16)y.z; h[7] = (_Float16)y.w;
    *reinterpret_cast<half8*>(out + i) = h;
}

// ---------------- fused masked attention, flash-style ----------------
// 512 threads = 8 waves. QK role: wave (rg = wid>>1 row-group of 16 rows,
// ch = wid&1 col-half of 32 keys), 2 S-fragments/wave. PV role: wave owns
// output feat cols [64*wid, 64*wid+64), all 64 rows (4x4 fragments).
// MFMA 16x16x32 f16. C layout (m89-verified): col = lane&15, row = (lane>>4)*4+reg.
// A: row = lane&15, k = (lane>>4)*8+j ; B: col = lane&15, same k map (A/B use the
// identical k-grouping, so QK and PV are k-permutation-invariant).
template<bool RH>
__global__ __launch_bounds__(512, 2)
void attn_main(const float* __restrict__ featf, const _Float16* __restrict__ feath,
               const int* __restrict__ Amat, float* __restrict__ out) {
    __shared__ alignas(16) _Float16 kv[BN * KV_STRIDE];   // 66560 B, K and V tile
    __shared__ alignas(16) _Float16 pbuf[BM][72];          // 9216 B, P (probs)
    __shared__ alignas(16) float pmax[BM][2];
    __shared__ alignas(16) float psum[BM][2];
    __shared__ alignas(16) float m_s[BM];
    __shared__ alignas(16) float l_s[BM];
    __shared__ alignas(16) float rscale[BM];

    const int tid  = threadIdx.x;
    const int lane = tid & 63;
    const int wid  = tid >> 6;      // 0..7
    const int g    = lane >> 4;     // 0..3 (k-group)
    const int a    = lane & 15;     // 0..15
    const int rg   = wid >> 1;      // QK row-group
    const int ch   = wid & 1;       // QK col-half
    const int qrow0 = blockIdx.x * BM;

    // ---- Q fragments: registers, loaded once (A-operand row = lane&15) ----
    half8 qf[16];
    {
        const int qr = qrow0 + 16 * rg + a;
#pragma unroll
        for (int ks = 0; ks < 16; ++ks) {
            const int f0 = 32 * ks + 8 * g;
            if constexpr (RH) {
                qf[ks] = *reinterpret_cast<const half8*>(feath + (size_t)qr * FF + f0);
            } else {
                const float* sp = featf + (size_t)qr * FF + f0;
                float4 x = *reinterpret_cast<const float4*>(sp);
                float4 y = *reinterpret_cast<const float4*>(sp + 4);
                half8 h;
                h[0] = (_Float16)x.x; h[1] = (_Float16)x.y; h[2] = (_Float16)x.z; h[3] = (_Float16)x.w;
                h[4] = (_Float16)y.x; h[5] = (_Float16)y.y; h[6] = (_Float16)y.z; h[7] = (_Float16)y.w;
                qf[ks] = h;
            }
        }
    }

    f32x4 acc[4][4];
#pragma unroll
    for (int i = 0; i < 4; ++i)
#pragma unroll
        for (int j = 0; j < 4; ++j) acc[i][j] = f32x4{0.f, 0.f, 0.f, 0.f};

    if (tid < BM) { m_s[tid] = -INFINITY; l_s[tid] = 0.f; }
    __syncthreads();

    for (int kt = 0; kt < NN / BN; ++kt) {
        const int key0 = kt * BN;

        // ---- stage kv tile (fp16), block-rotated: block b of key at slot (b+key/8)&63 ----
#pragma unroll
        for (int i = 0; i < 8; ++i) {
            const int flat8 = tid + i * 512;            // 0..4095
            const int key   = flat8 >> 6;               // 0..63
            const int b     = flat8 & 63;               // 8-feat block
            const int slot  = (b + (key >> 3)) & 63;
            _Float16* dst = &kv[key * KV_STRIDE + slot * 8];
            if constexpr (RH) {
                *reinterpret_cast<half8*>(dst) =
                    *reinterpret_cast<const half8*>(feath + (size_t)(key0 + key) * FF + b * 8);
            } else {
                const float* sp = featf + (size_t)(key0 + key) * FF + b * 8;
                float4 x = *reinterpret_cast<const float4*>(sp);
                float4 y = *reinterpret_cast<const float4*>(sp + 4);
                half8 h;
                h[0] = (_Float16)x.x; h[1] = (_Float16)x.y; h[2] = (_Float16)x.z; h[3] = (_Float16)x.w;
                h[4] = (_Float16)y.x; h[5] = (_Float16)y.y; h[6] = (_Float16)y.z; h[7] = (_Float16)y.w;
                *reinterpret_cast<half8*>(dst) = h;
            }
        }

        // ---- prefetch A-mask for this wave's S fragments (HBM stream, covered by QK) ----
        int am[2][4];
#pragma unroll
        for (int fc = 0; fc < 2; ++fc)
#pragma unroll
            for (int r = 0; r < 4; ++r) {
                const int arow = qrow0 + 16 * rg + 4 * g + r;
                const int acol = key0 + 32 * ch + 16 * fc + a;
                am[fc][r] = Amat[(size_t)arow * NN + acol];
            }
        __syncthreads();

        // ---- QK^T: 2 fragments per wave, full 512-dim contraction ----
        f32x4 s0{0.f, 0.f, 0.f, 0.f}, s1{0.f, 0.f, 0.f, 0.f};
        const int bk0 = 32 * ch + a;        // kv row (key) for fc=0
        const int bk1 = bk0 + 16;           // fc=1
        const int kb0 = bk0 >> 3;
        const int kb1 = bk1 >> 3;
        const _Float16* kr0 = &kv[bk0 * KV_STRIDE];
        const _Float16* kr1 = &kv[bk1 * KV_STRIDE];
#pragma unroll
        for (int ks = 0; ks < 16; ++ks) {
            const int b = 4 * ks + g;
            const half8 bf0 = *reinterpret_cast<const half8*>(kr0 + (((b + kb0) & 63) << 3));
            const half8 bf1 = *reinterpret_cast<const half8*>(kr1 + (((b + kb1) & 63) << 3));
            s0 = __builtin_amdgcn_mfma_f32_16x16x32_f16(qf[ks], bf0, s0, 0, 0, 0);
            s1 = __builtin_amdgcn_mfma_f32_16x16x32_f16(qf[ks], bf1, s1, 0, 0, 0);
        }

        // ---- mask + per-row tile max (reduce across 16 col-lanes, then col-halves via LDS) ----
        float sv[2][4];
#pragma unroll
        for (int r = 0; r < 4; ++r) {
            sv[0][r] = (am[0][r] > 0) ? s0[r] : MASK_NEG;
            sv[1][r] = (am[1][r] > 0) ? s1[r] : MASK_NEG;
        }
#pragma unroll
        for (int r = 0; r < 4; ++r) {
            float v = fmaxf(sv[0][r], sv[1][r]);
            v = fmaxf(v, __shfl_xor(v, 1, 16));
            v = fmaxf(v, __shfl_xor(v, 2, 16));
            v = fmaxf(v, __shfl_xor(v, 4, 16));
            v = fmaxf(v, __shfl_xor(v, 8, 16));
            if (a == 0) pmax[16 * rg + 4 * g + r][ch] = v;
        }
        __syncthreads();

        // ---- P = exp(s - m_new), write fp16 P, per-row partial sums ----
#pragma unroll
        for (int r = 0; r < 4; ++r) {
            const int row = 16 * rg + 4 * g + r;
            const float mo = m_s[row];
            const float mn = fmaxf(mo, fmaxf(pmax[row][0], pmax[row][1]));
            const float p0 = __expf(sv[0][r] - mn);
            const float p1 = __expf(sv[1][r] - mn);
            pbuf[row][32 * ch + a]      = (_Float16)p0;
            pbuf[row][32 * ch + 16 + a] = (_Float16)p1;
            float ssum = p0 + p1;
            ssum += __shfl_xor(ssum, 1, 16);
            ssum += __shfl_xor(ssum, 2, 16);
            ssum += __shfl_xor(ssum, 4, 16);
            ssum += __shfl_xor(ssum, 8, 16);
            if (a == 0) psum[row][ch] = ssum;
        }
        __syncthreads();

        // ---- online-softmax stats update (one thread per row) ----
        if (tid < BM) {
            const float mo = m_s[tid];
            const float mn = fmaxf(mo, fmaxf(pmax[tid][0], pmax[tid][1]));
            const float sc = __expf(mo - mn);   // mo=-inf (first tile) -> 0
            l_s[tid] = l_s[tid] * sc + psum[tid][0] + psum[tid][1];
            m_s[tid] = mn;
            rscale[tid] = sc;
        }
        __syncthreads();

        // ---- rescale O, then PV (wave owns cols [64*wid, 64*wid+64)) ----
#pragma unroll
        for (int rf = 0; rf < 4; ++rf) {
            const float4 scv = *reinterpret_cast<const float4*>(&rscale[16 * rf + 4 * g]);
#pragma unroll
            for (int cf = 0; cf < 4; ++cf) {
                acc[rf][cf][0] *= scv.x; acc[rf][cf][1] *= scv.y;
                acc[rf][cf][2] *= scv.z; acc[rf][cf][3] *= scv.w;
            }
        }
#pragma unroll
        for (int kk = 0; kk < 2; ++kk) {
            half8 af[4];
#pragma unroll
            for (int rf = 0; rf < 4; ++rf)
                af[rf] = *reinterpret_cast<const half8*>(&pbuf[16 * rf + a][32 * kk + 8 * g]);
            const int keybase = 32 * kk + 8 * g;
#pragma unroll
            for (int cf = 0; cf < 4; ++cf) {
                const int col  = 64 * wid + 16 * cf + a;            // global feat col
                const int slot = (((col >> 3) + 4 * kk + g) & 63);  // rotation for key rows keybase..+7
                const _Float16* vb = &kv[(size_t)keybase * KV_STRIDE + (slot << 3) + (col & 7)];
                half8 bf;
#pragma unroll
                for (int j = 0; j < 8; ++j)
                    bf[j] = vb[j * KV_STRIDE];
#pragma unroll
                for (int rf = 0; rf < 4; ++rf)
                    acc[rf][cf] = __builtin_amdgcn_mfma_f32_16x16x32_f16(af[rf], bf, acc[rf][cf], 0, 0, 0);
            }
        }
        __syncthreads();
    }

    // ---- epilogue: O / l, write fp32 ----
#pragma unroll
    for (int rf = 0; rf < 4; ++rf) {
        const float4 lv = *reinterpret_cast<const float4*>(&l_s[16 * rf + 4 * g]);
        const float inv[4] = {1.f / lv.x, 1.f / lv.y, 1.f / lv.z, 1.f / lv.w};
#pragma unroll
        for (int cf = 0; cf < 4; ++cf) {
            const int col = 64 * wid + 16 * cf + a;
#pragma unroll
            for (int r = 0; r < 4; ++r) {
                out[(size_t)(qrow0 + 16 * rf + 4 * g + r) * FF + col] = acc[rf][cf][r] * inv[r];
            }
        }
    }
}

extern "C" void kernel_launch(void* const* d_in, const int* in_sizes, int n_in,
                              void* d_out, int out_size, void* d_ws, size_t ws_size,
                              hipStream_t stream) {
    const float* features = (const float*)d_in[0];
    const int*   Amat     = (const int*)d_in[1];
    float*       out      = (float*)d_out;

    const size_t half_bytes = (size_t)NN * FF * sizeof(_Float16);  // 12.58 MB
    const int grid = NN / BM;  // 192 blocks

    if (ws_size >= half_bytes) {
        _Float16* feath = (_Float16*)d_ws;
        cvt_feat_kernel<<<(NN * FF) / (256 * 8), 256, 0, stream>>>(features, feath);
        attn_main<true><<<grid, 512, 0, stream>>>(features, feath, Amat, out);
    } else {
        attn_main<false><<<grid, 512, 0, stream>>>(features, nullptr, Amat, out);
    }
}